// Round 3
// baseline (29.357 us; speedup 1.0000x reference)
//
#include <hip/hip_runtime.h>

// out[b,i] = sum_j A[z_b][i][j] * x[b,j]  -  dt * x[b,i]^3
// A[m] = dt*beta_m*W_m + diag(1 + dt*(mu_m + alpha_m*deg_m))
// W_m = sigmoid(0.5*(G_m + G_m^T)) with zero diagonal; deg_m = row-sum of W_m.

typedef float fvec4 __attribute__((ext_vector_type(4)));   // native vector: OK for nontemporal builtins

__global__ __launch_bounds__(256) void bistable_kernel(
    const float* __restrict__ X,          // (B,4)
    const int*   __restrict__ z,          // (B,)
    const float* __restrict__ dt_val,     // (1,)
    const float* __restrict__ G,          // (4,4,4)
    const float* __restrict__ mu_logits,  // (4,4)
    const float* __restrict__ alpha_p,    // (4,)
    const float* __restrict__ beta_p,     // (4,)
    float* __restrict__ out,              // (B,4)
    int Bn)
{
    __shared__ float A[4 * 16];
    __shared__ float s_dt;

    const int t = threadIdx.x;
    if (t < 16) {
        const int m = t >> 2;      // mode
        const int i = t & 3;       // row
        const float dt = dt_val[0];
        float w[4];
        float deg = 0.0f;
        #pragma unroll
        for (int j = 0; j < 4; ++j) {
            float s = 0.5f * (G[m * 16 + i * 4 + j] + G[m * 16 + j * 4 + i]);
            float wv = 1.0f / (1.0f + __expf(-s));
            if (j == i) wv = 0.0f;   // zero diagonal
            w[j] = wv;
            deg += wv;
        }
        const float mu = 0.1f + 1.4f / (1.0f + __expf(-mu_logits[m * 4 + i]));
        const float a = alpha_p[m];
        const float b = beta_p[m];
        float arow[4];
        #pragma unroll
        for (int j = 0; j < 4; ++j) arow[j] = dt * b * w[j];
        arow[i] = 1.0f + dt * (mu + a * deg);   // fold diag (W diag is 0)
        #pragma unroll
        for (int j = 0; j < 4; ++j) A[m * 16 + i * 4 + j] = arow[j];
    }
    if (t == 0) s_dt = dt_val[0];
    __syncthreads();

    const float dt = s_dt;
    const fvec4* __restrict__ X4 = (const fvec4*)X;
    fvec4* __restrict__ O4 = (fvec4*)out;

    const int tid = blockIdx.x * blockDim.x + t;
    const int stride = gridDim.x * blockDim.x;

    auto body = [&](const fvec4& xv, int m, fvec4& ov) {
        const float* __restrict__ a = &A[m * 16];
        const float x0 = xv.x, x1 = xv.y, x2 = xv.z, x3 = xv.w;
        ov.x = a[0]  * x0 + a[1]  * x1 + a[2]  * x2 + a[3]  * x3 - dt * x0 * x0 * x0;
        ov.y = a[4]  * x0 + a[5]  * x1 + a[6]  * x2 + a[7]  * x3 - dt * x1 * x1 * x1;
        ov.z = a[8]  * x0 + a[9]  * x1 + a[10] * x2 + a[11] * x3 - dt * x2 * x2 * x2;
        ov.w = a[12] * x0 + a[13] * x1 + a[14] * x2 + a[15] * x3 - dt * x3 * x3 * x3;
    };

    int idx = tid;
    // main: 4 independent items in flight per wave (stride-separated => each
    // load instruction stays perfectly lane-contiguous)
    for (; idx + 3 * stride < Bn; idx += 4 * stride) {
        const int i0 = idx, i1 = idx + stride, i2 = idx + 2 * stride, i3 = idx + 3 * stride;
        const fvec4 x0 = X4[i0];
        const fvec4 x1 = X4[i1];
        const fvec4 x2 = X4[i2];
        const fvec4 x3 = X4[i3];
        const int m0 = z[i0], m1 = z[i1], m2 = z[i2], m3 = z[i3];
        fvec4 o0, o1, o2, o3;
        body(x0, m0, o0);
        body(x1, m1, o1);
        body(x2, m2, o2);
        body(x3, m3, o3);
        __builtin_nontemporal_store(o0, &O4[i0]);
        __builtin_nontemporal_store(o1, &O4[i1]);
        __builtin_nontemporal_store(o2, &O4[i2]);
        __builtin_nontemporal_store(o3, &O4[i3]);
    }
    // tail
    for (; idx < Bn; idx += stride) {
        const fvec4 xv = X4[idx];
        const int m = z[idx];
        fvec4 ov;
        body(xv, m, ov);
        __builtin_nontemporal_store(ov, &O4[idx]);
    }
}

extern "C" void kernel_launch(void* const* d_in, const int* in_sizes, int n_in,
                              void* d_out, int out_size, void* d_ws, size_t ws_size,
                              hipStream_t stream) {
    const float* X         = (const float*)d_in[0];
    const int*   z         = (const int*)d_in[1];
    const float* dt_val    = (const float*)d_in[2];
    const float* G         = (const float*)d_in[3];
    const float* mu_logits = (const float*)d_in[4];
    const float* alpha_p   = (const float*)d_in[5];
    const float* beta_p    = (const float*)d_in[6];
    float* out = (float*)d_out;

    const int Bn = in_sizes[1];   // number of items (z count)

    const int block = 256;
    int grid = (Bn + block - 1) / block;
    if (grid > 4096) grid = 4096;   // B=4.19M -> exactly one unrolled pass of 4

    bistable_kernel<<<grid, block, 0, stream>>>(X, z, dt_val, G, mu_logits,
                                                alpha_p, beta_p, out, Bn);
}

// Round 4
// 28.238 us; speedup vs baseline: 1.0396x; 1.0396x over previous
//
#include <hip/hip_runtime.h>

// out[b,i] = sum_j A[z_b][i][j] * x[b,j]  -  dt * x[b,i]^3
// A[m] = dt*beta_m*W_m + diag(1 + dt*(mu_m + alpha_m*deg_m))
// W_m = sigmoid(0.5*(G_m + G_m^T)) with zero diagonal; deg_m = row-sum of W_m.

typedef float fvec4 __attribute__((ext_vector_type(4)));

__global__ __launch_bounds__(256) void bistable_kernel(
    const float* __restrict__ X,          // (B,4)
    const int*   __restrict__ z,          // (B,)
    const float* __restrict__ dt_val,     // (1,)
    const float* __restrict__ G,          // (4,4,4)
    const float* __restrict__ mu_logits,  // (4,4)
    const float* __restrict__ alpha_p,    // (4,)
    const float* __restrict__ beta_p,     // (4,)
    float* __restrict__ out,              // (B,4)
    int Bn)
{
    __shared__ float A[4 * 16];
    __shared__ float s_dt;

    const int t = threadIdx.x;
    if (t < 16) {
        const int m = t >> 2;      // mode
        const int i = t & 3;       // row
        const float dt = dt_val[0];
        float w[4];
        float deg = 0.0f;
        #pragma unroll
        for (int j = 0; j < 4; ++j) {
            float s = 0.5f * (G[m * 16 + i * 4 + j] + G[m * 16 + j * 4 + i]);
            float wv = 1.0f / (1.0f + __expf(-s));
            if (j == i) wv = 0.0f;   // zero diagonal
            w[j] = wv;
            deg += wv;
        }
        const float mu = 0.1f + 1.4f / (1.0f + __expf(-mu_logits[m * 4 + i]));
        const float a = alpha_p[m];
        const float b = beta_p[m];
        float arow[4];
        #pragma unroll
        for (int j = 0; j < 4; ++j) arow[j] = dt * b * w[j];
        arow[i] = 1.0f + dt * (mu + a * deg);   // fold diag (W diag is 0)
        #pragma unroll
        for (int j = 0; j < 4; ++j) A[m * 16 + i * 4 + j] = arow[j];
    }
    if (t == 0) s_dt = dt_val[0];
    __syncthreads();

    const float dt = s_dt;
    const fvec4* __restrict__ X4 = (const fvec4*)X;
    fvec4* __restrict__ O4 = (fvec4*)out;

    const int tid = blockIdx.x * blockDim.x + t;
    const int stride = gridDim.x * blockDim.x;   // 2048*256 = 524288; B/stride = 8 iters

    auto body = [&](const fvec4& xv, int m, fvec4& ov) {
        const float* __restrict__ a = &A[m * 16];
        const float x0 = xv.x, x1 = xv.y, x2 = xv.z, x3 = xv.w;
        ov.x = a[0]  * x0 + a[1]  * x1 + a[2]  * x2 + a[3]  * x3 - dt * x0 * x0 * x0;
        ov.y = a[4]  * x0 + a[5]  * x1 + a[6]  * x2 + a[7]  * x3 - dt * x1 * x1 * x1;
        ov.z = a[8]  * x0 + a[9]  * x1 + a[10] * x2 + a[11] * x3 - dt * x2 * x2 * x2;
        ov.w = a[12] * x0 + a[13] * x1 + a[14] * x2 + a[15] * x3 - dt * x3 * x3 * x3;
    };

    if (tid >= Bn) return;

    // depth-2 software pipeline: while computing item k, items k+1 and k+2
    // have their X/z loads in flight. Named registers only (no runtime-indexed
    // arrays -> no scratch).
    fvec4 xa, xb, xn;
    int   ma, mb, mn;

    int idx = tid;
    xa = X4[idx]; ma = z[idx];
    {
        const int i1 = idx + stride;
        if (i1 < Bn) { xb = X4[i1]; mb = z[i1]; }
        else         { xb = xa;     mb = 0;     }
    }

    for (;;) {
        const int i2 = idx + 2 * stride;
        const bool have2 = (i2 < Bn);
        if (have2) { xn = X4[i2]; mn = z[i2]; }   // prefetch depth-2

        fvec4 ov;
        body(xa, ma, ov);
        __builtin_nontemporal_store(ov, &O4[idx]);

        idx += stride;
        if (idx >= Bn) break;
        xa = xb; ma = mb;
        if (have2) { xb = xn; mb = mn; }
    }
}

extern "C" void kernel_launch(void* const* d_in, const int* in_sizes, int n_in,
                              void* d_out, int out_size, void* d_ws, size_t ws_size,
                              hipStream_t stream) {
    const float* X         = (const float*)d_in[0];
    const int*   z         = (const int*)d_in[1];
    const float* dt_val    = (const float*)d_in[2];
    const float* G         = (const float*)d_in[3];
    const float* mu_logits = (const float*)d_in[4];
    const float* alpha_p   = (const float*)d_in[5];
    const float* beta_p    = (const float*)d_in[6];
    float* out = (float*)d_out;

    const int Bn = in_sizes[1];   // number of items (z count)

    const int block = 256;
    int grid = (Bn + block - 1) / block;
    if (grid > 2048) grid = 2048;   // exactly 8 blocks/CU resident: one occupancy generation

    bistable_kernel<<<grid, block, 0, stream>>>(X, z, dt_val, G, mu_logits,
                                                alpha_p, beta_p, out, Bn);
}